// Round 5
// baseline (441.472 us; speedup 1.0000x reference)
//
#include <hip/hip_runtime.h>

typedef __bf16 bf16;
typedef __bf16 bf16x4 __attribute__((ext_vector_type(4)));
typedef __bf16 bf16x8 __attribute__((ext_vector_type(8)));
typedef float f32x4 __attribute__((ext_vector_type(4)));

#define LOG2E 1.44269504088896f

// async global->LDS, 16B per lane. LDS dest is wave-uniform base + lane*16
// (m104/m108): pass the lane-0 pointer; generic->AS(3) = low-32-bit truncation.
__device__ __forceinline__ void gl_lds16(const bf16* g, bf16* l) {
  __builtin_amdgcn_global_load_lds(
      reinterpret_cast<const __attribute__((address_space(1))) void*>((uintptr_t)g),
      reinterpret_cast<__attribute__((address_space(3))) void*>((uint32_t)(uintptr_t)l),
      16, 0, 0);
}

// ---------------- cast fp32 -> bf16 for weights + pm, and build RoPE cos/sin table ----------------
__global__ void cast3_kernel(const float* __restrict__ a, int na4, bf16* __restrict__ oa,
                             const float* __restrict__ b, int nb4, bf16* __restrict__ ob,
                             const float* __restrict__ c, int nc4, bf16* __restrict__ oc,
                             float2* __restrict__ tab, int nt) {
  int i = blockIdx.x * blockDim.x + threadIdx.x;
  if (i < na4 + nb4 + nc4) {
    const float* src; bf16* dst; int idx;
    if (i < na4)            { src = a; dst = oa; idx = i; }
    else if (i < na4 + nb4) { src = b; dst = ob; idx = i - na4; }
    else                    { src = c; dst = oc; idx = i - na4 - nb4; }
    float4 v = ((const float4*)src)[idx];
    bf16x4 o = { (bf16)v.x, (bf16)v.y, (bf16)v.z, (bf16)v.w };
    ((bf16x4*)dst)[idx] = o;
  } else {
    int idx = i - (na4 + nb4 + nc4);
    if (idx >= nt) return;
    int pos = idx >> 5, fi = idx & 31;
    float inv = exp2f((float)fi * -0.41524101186f);   // 10000^(-fi/32)
    float th = (float)pos * inv;
    float sn, cs;
    sincosf(th, &sn, &cs);
    tab[idx] = make_float2(cs, sn);
  }
}

// ---------------- RMSNorm: seq fp32 [8192][1024] -> x bf16 ----------------
__global__ __launch_bounds__(256) void rmsnorm_kernel(const float* __restrict__ seq,
                                                      const float* __restrict__ g,
                                                      bf16* __restrict__ xbf) {
  int row = blockIdx.x;
  int t = threadIdx.x;
  float4 x = ((const float4*)(seq + (size_t)row * 1024))[t];
  float ss = x.x*x.x + x.y*x.y + x.z*x.z + x.w*x.w;
  #pragma unroll
  for (int m = 32; m >= 1; m >>= 1) ss += __shfl_xor(ss, m, 64);
  __shared__ float red[4];
  if ((t & 63) == 0) red[t >> 6] = ss;
  __syncthreads();
  float tot = red[0] + red[1] + red[2] + red[3];
  float scale = rsqrtf(tot * (1.0f / 1024.0f) + 1.1920929e-07f);
  float4 gv = ((const float4*)g)[t];
  bf16x4 o = { (bf16)(x.x*scale*gv.x), (bf16)(x.y*scale*gv.y),
               (bf16)(x.z*scale*gv.z), (bf16)(x.w*scale*gv.w) };
  ((bf16x4*)(xbf + (size_t)row * 1024))[t] = o;
}

// ---------------- GEMM C[M,N] = A[M,K] * B[N,K]^T  (bf16 in, bf16/fp32 out) ----------------
// BK=64, XOR-swizzled LDS, global_load_lds width=16 (m97 lineage).
template<int OUTF>
__global__ __launch_bounds__(256) void gemm_bt_kernel(const bf16* __restrict__ A,
                                                      const bf16* __restrict__ B,
                                                      void* __restrict__ C,
                                                      int M, int N, int K) {
  __shared__ bf16 As[128 * 64];
  __shared__ bf16 Bs[128 * 64];
  int t = threadIdx.x;
  int lane = t & 63, wv = t >> 6;
  int m16 = lane & 15, quad = lane >> 4;
  int bn = blockIdx.x, bm = blockIdx.y;
  const bf16* Ab = A + (size_t)bm * 128 * K;
  const bf16* Bb = B + (size_t)bn * 128 * K;
  int wr = (wv >> 1) * 64, wc = (wv & 1) * 64;
  f32x4 acc[4][4] = {};
  for (int k0 = 0; k0 < K; k0 += 64) {
    #pragma unroll
    for (int i = 0; i < 4; i++) {
      int cb = i * 256 + wv * 64;          // wave-uniform chunk base (16B chunks)
      int s = cb + lane;
      int row = s >> 3, p = s & 7, g = p ^ (row & 7);
      gl_lds16(Ab + (size_t)row * K + k0 + g * 8, &As[cb * 8]);
      gl_lds16(Bb + (size_t)row * K + k0 + g * 8, &Bs[cb * 8]);
    }
    __syncthreads();   // implicit s_waitcnt vmcnt(0) drains the LDS-DMA
    #pragma unroll
    for (int kk = 0; kk < 2; kk++) {
      bf16x8 af[4], bfr[4];
      #pragma unroll
      for (int i = 0; i < 4; i++) {
        int row = wr + i * 16 + m16;
        int p = (kk * 4 + quad) ^ (row & 7);
        af[i] = *(const bf16x8*)(&As[row * 64 + p * 8]);
      }
      #pragma unroll
      for (int j = 0; j < 4; j++) {
        int row = wc + j * 16 + m16;
        int p = (kk * 4 + quad) ^ (row & 7);
        bfr[j] = *(const bf16x8*)(&Bs[row * 64 + p * 8]);
      }
      #pragma unroll
      for (int i = 0; i < 4; i++)
        #pragma unroll
        for (int j = 0; j < 4; j++)
          acc[i][j] = __builtin_amdgcn_mfma_f32_16x16x32_bf16(af[i], bfr[j], acc[i][j], 0, 0, 0);
    }
    __syncthreads();
  }
  #pragma unroll
  for (int i = 0; i < 4; i++)
    #pragma unroll
    for (int j = 0; j < 4; j++)
      #pragma unroll
      for (int r = 0; r < 4; r++) {
        size_t row = (size_t)bm * 128 + wr + i * 16 + quad * 4 + r;
        size_t col = (size_t)bn * 128 + wc + j * 16 + m16;
        float v = acc[i][j][r];
        if (OUTF) ((float*)C)[row * N + col] = v;
        else      ((bf16*)C)[row * N + col] = (bf16)v;
      }
}

// ---------------- attention pass body: fixed NT tiles (compile-time -> full pipelining) ----------------
// NT=17 covers qi 0..15, NT=33 covers qi 16..31. Tile 0 = persistent-mem K read
// straight from global (L2-resident); tiles 1..NT-1 from Ks (seq rows).
// Masked-out lanes get -1e30 -> exp 0 (included in sum/PV harmlessly).
template<int NT>
__device__ __forceinline__ void attn_pass(int qi, const bf16* qk_base, const bf16* pmk_h,
                                          const bf16* Ks, const bf16* Vt, bf16* myP,
                                          const float2* tab, bf16* ob,
                                          int bw, int h, int seg, int m16, int quad) {
  int q0 = qi * 16;
  int qrow = q0 + m16;
  int pos = seg * 512 + qrow;
  const bf16* qp = qk_base + (size_t)qrow * 3072;
  // load Q frags + rope + 1/8 scale in registers
  bf16 qr0[8], qr1[8];
  *(uint4*)qr0 = *(const uint4*)(qp + quad * 8);
  *(uint4*)qr1 = *(const uint4*)(qp + 32 + quad * 8);
  {
    const float2* tb0 = tab + pos * 32 + quad * 4;
    const float2* tb1 = tb0 + 16;
    #pragma unroll
    for (int p = 0; p < 4; p++) {
      float2 c0 = tb0[p], c1 = tb1[p];
      float a0 = (float)qr0[2 * p], a1 = (float)qr0[2 * p + 1];
      qr0[2 * p]     = (bf16)((a0 * c0.x - a1 * c0.y) * 0.125f);
      qr0[2 * p + 1] = (bf16)((a1 * c0.x + a0 * c0.y) * 0.125f);
      float b0 = (float)qr1[2 * p], b1 = (float)qr1[2 * p + 1];
      qr1[2 * p]     = (bf16)((b0 * c1.x - b1 * c1.y) * 0.125f);
      qr1[2 * p + 1] = (bf16)((b1 * c1.x + b0 * c1.y) * 0.125f);
    }
  }
  bf16x8 qf0 = *(bf16x8*)qr0;
  bf16x8 qf1 = *(bf16x8*)qr1;
  f32x4 s[NT];
  {   // tile 0: pm K from global
    f32x4 acc = {0.f, 0.f, 0.f, 0.f};
    bf16x8 b0 = *(const bf16x8*)(pmk_h + (size_t)m16 * 64 + quad * 8);
    bf16x8 b1 = *(const bf16x8*)(pmk_h + (size_t)m16 * 64 + 32 + quad * 8);
    acc = __builtin_amdgcn_mfma_f32_16x16x32_bf16(qf0, b0, acc, 0, 0, 0);
    acc = __builtin_amdgcn_mfma_f32_16x16x32_bf16(qf1, b1, acc, 0, 0, 0);
    s[0] = acc;
  }
  #pragma unroll
  for (int tl = 1; tl < NT; tl++) {
    f32x4 acc = {0.f, 0.f, 0.f, 0.f};
    int row = (tl - 1) * 16 + m16;          // seq K row
    bf16x8 b0 = *(const bf16x8*)(&Ks[row * 72 + quad * 8]);
    bf16x8 b1 = *(const bf16x8*)(&Ks[row * 72 + 32 + quad * 8]);
    acc = __builtin_amdgcn_mfma_f32_16x16x32_bf16(qf0, b0, acc, 0, 0, 0);
    acc = __builtin_amdgcn_mfma_f32_16x16x32_bf16(qf1, b1, acc, 0, 0, 0);
    s[tl] = acc;
  }
  // causal mask: query i sees kv j iff j-16 <= i  (tile 0 j<16 always visible)
  #pragma unroll
  for (int tl = 0; tl < NT; tl++) {
    int j = tl * 16 + m16 - 16;
    #pragma unroll
    for (int r = 0; r < 4; r++) {
      int i = q0 + quad * 4 + r;
      if (j > i) s[tl][r] = -1e30f;
    }
  }
  // softmax: reduce over NT tiles + 16 lanes of the column group
  float lrow[4];
  #pragma unroll
  for (int r = 0; r < 4; r++) {
    float mx = s[0][r];
    #pragma unroll
    for (int tl = 1; tl < NT; tl++) mx = fmaxf(mx, s[tl][r]);
    mx = fmaxf(mx, __shfl_xor(mx, 1, 64));
    mx = fmaxf(mx, __shfl_xor(mx, 2, 64));
    mx = fmaxf(mx, __shfl_xor(mx, 4, 64));
    mx = fmaxf(mx, __shfl_xor(mx, 8, 64));
    float sum = 0.f;
    #pragma unroll
    for (int tl = 0; tl < NT; tl++) {
      float p = exp2f((s[tl][r] - mx) * LOG2E);
      s[tl][r] = p;
      sum += p;
    }
    sum += __shfl_xor(sum, 1, 64);
    sum += __shfl_xor(sum, 2, 64);
    sum += __shfl_xor(sum, 4, 64);
    sum += __shfl_xor(sum, 8, 64);
    lrow[r] = sum;
  }
  // PV: chunks of 32 kv; ragged tail tile zero-filled. No explicit drains —
  // compiler inserts fine-grained lgkmcnt for the write->read dependency.
  constexpr int NC = (NT + 1) / 2;
  f32x4 o[4] = {};
  #pragma unroll
  for (int c = 0; c < NC; c++) {
    #pragma unroll
    for (int half = 0; half < 2; half++) {
      int tl = 2 * c + half;
      #pragma unroll
      for (int r = 0; r < 4; r++) {
        float pv = (tl < NT) ? s[tl][r] : 0.f;
        myP[(quad * 4 + r) * 40 + half * 16 + m16] = (bf16)pv;
      }
    }
    bf16x8 pf = *(const bf16x8*)(&myP[m16 * 40 + quad * 8]);
    #pragma unroll
    for (int dt = 0; dt < 4; dt++) {
      bf16x8 vf = *(const bf16x8*)(&Vt[(dt * 16 + m16) * 536 + c * 32 + quad * 8]);
      o[dt] = __builtin_amdgcn_mfma_f32_16x16x32_bf16(pf, vf, o[dt], 0, 0, 0);
    }
  }
  // normalize + write to [8192][1024] merged layout
  float invl[4];
  #pragma unroll
  for (int r = 0; r < 4; r++) invl[r] = 1.0f / lrow[r];
  #pragma unroll
  for (int dt = 0; dt < 4; dt++)
    #pragma unroll
    for (int r = 0; r < 4; r++) {
      size_t row = (size_t)bw * 512 + q0 + quad * 4 + r;
      ob[row * 1024 + h * 64 + dt * 16 + m16] = (bf16)(o[dt][r] * invl[r]);
    }
}

// ---------------- attention: one block per (bw,h), 16 waves (1024 thr) ----------------
__global__ __launch_bounds__(1024) void attn_kernel(const bf16* __restrict__ qkv,
                                                    const bf16* __restrict__ pmbf,
                                                    const float2* __restrict__ tab,
                                                    bf16* __restrict__ ob) {
  __shared__ bf16 Ks[512 * 72];          // seq K rows only (rope'd), stride 72
  __shared__ bf16 Vt[64 * 536 + 16];     // V^T [d][j] incl pm, stride 536, padded tail
  __shared__ bf16 Pb[16 * 16 * 40];      // per-wave P staging, stride 40
  int bh = blockIdx.x;
  int bw = bh >> 4, h = bh & 15;
  int seg = bw & 7;
  int t = threadIdx.x;
  int wv = t >> 6, lane = t & 63;
  int m16 = lane & 15, quad = lane >> 4;
  const bf16* qk_base = qkv + (size_t)bw * 512 * 3072 + h * 64;  // row s at +s*3072; K +1024; V +2048
  const bf16* pmk_h = pmbf + (size_t)h * 1024;                    // pm K head h [16][64]
  // stage seq K rows with rope: 512 rows x 8 chunks = 4096, 4 iters
  #pragma unroll
  for (int it = 0; it < 4; it++) {
    int ch = t + it * 1024;
    int row = ch >> 3, c8 = (ch & 7) * 8;
    bf16 tmp[8];
    *(uint4*)tmp = *(const uint4*)(qk_base + (size_t)row * 3072 + 1024 + c8);
    int pos = seg * 512 + row;
    const float2* tb = tab + pos * 32 + (c8 >> 1);
    #pragma unroll
    for (int p = 0; p < 4; p++) {
      float2 cs = tb[p];
      float x0 = (float)tmp[2 * p], x1 = (float)tmp[2 * p + 1];
      tmp[2 * p]     = (bf16)(x0 * cs.x - x1 * cs.y);
      tmp[2 * p + 1] = (bf16)(x1 * cs.x + x0 * cs.y);
    }
    *(uint4*)(&Ks[row * 72 + c8]) = *(uint4*)tmp;
  }
  // stage V transposed, d0-major so a wave's lanes span rows (conflict-free stores)
  {
    int r512 = t & 511;
    #pragma unroll
    for (int it = 0; it < 4; it++) {
      int d0 = ((t >> 9) * 4 + it) * 8;
      #pragma unroll
      for (int rep = 0; rep < 2; rep++) {
        int row = rep ? (512 + r512) : r512;
        if (rep == 0 || r512 < 16) {
          bf16 tmp[8];
          if (row < 16) *(uint4*)tmp = *(const uint4*)(pmbf + ((size_t)(16 + h) * 16 + row) * 64 + d0);
          else          *(uint4*)tmp = *(const uint4*)(qk_base + (size_t)(row - 16) * 3072 + 2048 + d0);
          #pragma unroll
          for (int i = 0; i < 8; i++) Vt[(d0 + i) * 536 + row] = tmp[i];
        }
      }
    }
  }
  // zero-pad Vt cols 528..535 (avoid NaN garbage; multiplied by P=0) and tail
  if (t < 512) { int r = t >> 3, cc = 528 + (t & 7); Vt[r * 536 + cc] = (bf16)0.f; }
  if (t < 16) Vt[64 * 536 + t] = (bf16)0.f;
  __syncthreads();

  bf16* myP = &Pb[wv * 16 * 40];
  attn_pass<17>(wv,      qk_base, pmk_h, Ks, Vt, myP, tab, ob, bw, h, seg, m16, quad);
  attn_pass<33>(16 + wv, qk_base, pmk_h, Ks, Vt, myP, tab, ob, bw, h, seg, m16, quad);
}

// ---------------- launch ----------------
extern "C" void kernel_launch(void* const* d_in, const int* in_sizes, int n_in,
                              void* d_out, int out_size, void* d_ws, size_t ws_size,
                              hipStream_t stream) {
  const float* seq  = (const float*)d_in[0];
  const float* g    = (const float*)d_in[1];
  const float* wqkv = (const float*)d_in[2];
  const float* wout = (const float*)d_in[3];
  const float* pm   = (const float*)d_in[4];
  float* out = (float*)d_out;
  char* ws = (char*)d_ws;
  bf16*   wqkv_bf = (bf16*)(ws);                  //  6,291,456
  bf16*   wout_bf = (bf16*)(ws + 6291456);        //  2,097,152
  bf16*   pm_bf   = (bf16*)(ws + 8388608);        //     65,536
  float2* tab     = (float2*)(ws + 8454144);      //  1,048,576 (4096 x 32 cos/sin)
  bf16*   x_bf    = (bf16*)(ws + 9502720);        // 16,777,216 (RMSNorm out, reused as attn out)
  bf16*   qkv_bf  = (bf16*)(ws + 26279936);       // 50,331,648 -> 76,611,584 total

  cast3_kernel<<<4640, 256, 0, stream>>>(wqkv, 786432, wqkv_bf,
                                         wout, 262144, wout_bf,
                                         pm, 8192, pm_bf,
                                         tab, 131072);
  rmsnorm_kernel<<<8192, 256, 0, stream>>>(seq, g, x_bf);
  gemm_bt_kernel<0><<<dim3(24, 64), 256, 0, stream>>>(x_bf, wqkv_bf, qkv_bf, 8192, 3072, 1024);
  attn_kernel<<<256, 1024, 0, stream>>>(qkv_bf, pm_bf, tab, x_bf);
  gemm_bt_kernel<1><<<dim3(8, 64), 256, 0, stream>>>(x_bf, wout_bf, out, 8192, 1024, 1024);
}

// Round 6
// 259.535 us; speedup vs baseline: 1.7010x; 1.7010x over previous
//
#include <hip/hip_runtime.h>

typedef __bf16 bf16;
typedef __bf16 bf16x4 __attribute__((ext_vector_type(4)));
typedef __bf16 bf16x8 __attribute__((ext_vector_type(8)));
typedef float f32x4 __attribute__((ext_vector_type(4)));

#define LOG2E 1.44269504088896f

// async global->LDS, 16B per lane. LDS dest is wave-uniform base + lane*16
// (m104/m108): pass the lane-0 pointer; generic->AS(3) = low-32-bit truncation.
__device__ __forceinline__ void gl_lds16(const bf16* g, bf16* l) {
  __builtin_amdgcn_global_load_lds(
      reinterpret_cast<const __attribute__((address_space(1))) void*>((uintptr_t)g),
      reinterpret_cast<__attribute__((address_space(3))) void*>((uint32_t)(uintptr_t)l),
      16, 0, 0);
}

// ---------------- cast fp32 -> bf16 for weights + pm, and build RoPE cos/sin table ----------------
__global__ void cast3_kernel(const float* __restrict__ a, int na4, bf16* __restrict__ oa,
                             const float* __restrict__ b, int nb4, bf16* __restrict__ ob,
                             const float* __restrict__ c, int nc4, bf16* __restrict__ oc,
                             float2* __restrict__ tab, int nt) {
  int i = blockIdx.x * blockDim.x + threadIdx.x;
  if (i < na4 + nb4 + nc4) {
    const float* src; bf16* dst; int idx;
    if (i < na4)            { src = a; dst = oa; idx = i; }
    else if (i < na4 + nb4) { src = b; dst = ob; idx = i - na4; }
    else                    { src = c; dst = oc; idx = i - na4 - nb4; }
    float4 v = ((const float4*)src)[idx];
    bf16x4 o = { (bf16)v.x, (bf16)v.y, (bf16)v.z, (bf16)v.w };
    ((bf16x4*)dst)[idx] = o;
  } else {
    int idx = i - (na4 + nb4 + nc4);
    if (idx >= nt) return;
    int pos = idx >> 5, fi = idx & 31;
    float inv = exp2f((float)fi * -0.41524101186f);   // 10000^(-fi/32)
    float th = (float)pos * inv;
    float sn, cs;
    sincosf(th, &sn, &cs);
    tab[idx] = make_float2(cs, sn);
  }
}

// ---------------- RMSNorm: seq fp32 [8192][1024] -> x bf16 ----------------
__global__ __launch_bounds__(256) void rmsnorm_kernel(const float* __restrict__ seq,
                                                      const float* __restrict__ g,
                                                      bf16* __restrict__ xbf) {
  int row = blockIdx.x;
  int t = threadIdx.x;
  float4 x = ((const float4*)(seq + (size_t)row * 1024))[t];
  float ss = x.x*x.x + x.y*x.y + x.z*x.z + x.w*x.w;
  #pragma unroll
  for (int m = 32; m >= 1; m >>= 1) ss += __shfl_xor(ss, m, 64);
  __shared__ float red[4];
  if ((t & 63) == 0) red[t >> 6] = ss;
  __syncthreads();
  float tot = red[0] + red[1] + red[2] + red[3];
  float scale = rsqrtf(tot * (1.0f / 1024.0f) + 1.1920929e-07f);
  float4 gv = ((const float4*)g)[t];
  bf16x4 o = { (bf16)(x.x*scale*gv.x), (bf16)(x.y*scale*gv.y),
               (bf16)(x.z*scale*gv.z), (bf16)(x.w*scale*gv.w) };
  ((bf16x4*)(xbf + (size_t)row * 1024))[t] = o;
}

// ---------------- GEMM C[M,N] = A[M,K] * B[N,K]^T  (bf16 in, bf16/fp32 out) ----------------
// BK=64, XOR-swizzled LDS, global_load_lds width=16 (m97 lineage).
template<int OUTF>
__global__ __launch_bounds__(256) void gemm_bt_kernel(const bf16* __restrict__ A,
                                                      const bf16* __restrict__ B,
                                                      void* __restrict__ C,
                                                      int M, int N, int K) {
  __shared__ bf16 As[128 * 64];
  __shared__ bf16 Bs[128 * 64];
  int t = threadIdx.x;
  int lane = t & 63, wv = t >> 6;
  int m16 = lane & 15, quad = lane >> 4;
  int bn = blockIdx.x, bm = blockIdx.y;
  const bf16* Ab = A + (size_t)bm * 128 * K;
  const bf16* Bb = B + (size_t)bn * 128 * K;
  int wr = (wv >> 1) * 64, wc = (wv & 1) * 64;
  f32x4 acc[4][4] = {};
  for (int k0 = 0; k0 < K; k0 += 64) {
    #pragma unroll
    for (int i = 0; i < 4; i++) {
      int cb = i * 256 + wv * 64;          // wave-uniform chunk base (16B chunks)
      int s = cb + lane;
      int row = s >> 3, p = s & 7, g = p ^ (row & 7);
      gl_lds16(Ab + (size_t)row * K + k0 + g * 8, &As[cb * 8]);
      gl_lds16(Bb + (size_t)row * K + k0 + g * 8, &Bs[cb * 8]);
    }
    __syncthreads();   // implicit s_waitcnt vmcnt(0) drains the LDS-DMA
    #pragma unroll
    for (int kk = 0; kk < 2; kk++) {
      bf16x8 af[4], bfr[4];
      #pragma unroll
      for (int i = 0; i < 4; i++) {
        int row = wr + i * 16 + m16;
        int p = (kk * 4 + quad) ^ (row & 7);
        af[i] = *(const bf16x8*)(&As[row * 64 + p * 8]);
      }
      #pragma unroll
      for (int j = 0; j < 4; j++) {
        int row = wc + j * 16 + m16;
        int p = (kk * 4 + quad) ^ (row & 7);
        bfr[j] = *(const bf16x8*)(&Bs[row * 64 + p * 8]);
      }
      #pragma unroll
      for (int i = 0; i < 4; i++)
        #pragma unroll
        for (int j = 0; j < 4; j++)
          acc[i][j] = __builtin_amdgcn_mfma_f32_16x16x32_bf16(af[i], bfr[j], acc[i][j], 0, 0, 0);
    }
    __syncthreads();
  }
  #pragma unroll
  for (int i = 0; i < 4; i++)
    #pragma unroll
    for (int j = 0; j < 4; j++)
      #pragma unroll
      for (int r = 0; r < 4; r++) {
        size_t row = (size_t)bm * 128 + wr + i * 16 + quad * 4 + r;
        size_t col = (size_t)bn * 128 + wc + j * 16 + m16;
        float v = acc[i][j][r];
        if (OUTF) ((float*)C)[row * N + col] = v;
        else      ((bf16*)C)[row * N + col] = (bf16)v;
      }
}

// ---------------- attention helpers ----------------
__device__ __forceinline__ void load_q_frag(const bf16* qk_base, const float2* tab,
                                            int seg, int qi, int m16, int quad,
                                            bf16x8* f0, bf16x8* f1) {
  int qrow = qi * 16 + m16;
  const bf16* qp = qk_base + (size_t)qrow * 3072;
  bf16 qr0[8], qr1[8];
  *(uint4*)qr0 = *(const uint4*)(qp + quad * 8);
  *(uint4*)qr1 = *(const uint4*)(qp + 32 + quad * 8);
  const float2* tb0 = tab + (seg * 512 + qrow) * 32 + quad * 4;
  const float2* tb1 = tb0 + 16;
  #pragma unroll
  for (int p = 0; p < 4; p++) {
    float2 c0 = tb0[p], c1 = tb1[p];
    float a0 = (float)qr0[2 * p], a1 = (float)qr0[2 * p + 1];
    qr0[2 * p]     = (bf16)((a0 * c0.x - a1 * c0.y) * 0.125f);
    qr0[2 * p + 1] = (bf16)((a1 * c0.x + a0 * c0.y) * 0.125f);
    float b0 = (float)qr1[2 * p], b1 = (float)qr1[2 * p + 1];
    qr1[2 * p]     = (bf16)((b0 * c1.x - b1 * c1.y) * 0.125f);
    qr1[2 * p + 1] = (bf16)((b1 * c1.x + b0 * c1.y) * 0.125f);
  }
  *f0 = *(bf16x8*)qr0;
  *f1 = *(bf16x8*)qr1;
}

// Pass over NT score tiles for TWO q-tiles sharing every K/V fragment read.
// m=0 softmax: scores bounded (|s|<~30 << f32 overflow at 88) -> skip max pass,
// exp immediately, accumulate l, one cross-lane reduction at the end.
template<int NT>
__device__ __forceinline__ void attn_pass2(int qiA, int qiB, const bf16* qk_base,
                                           const bf16* pmk_h, const bf16* Ks,
                                           const bf16* Vt, bf16* myP,
                                           const float2* tab, bf16* ob,
                                           int bw, int h, int seg, int m16, int quad) {
  bf16x8 qA0, qA1, qB0, qB1;
  load_q_frag(qk_base, tab, seg, qiA, m16, quad, &qA0, &qA1);
  load_q_frag(qk_base, tab, seg, qiB, m16, quad, &qB0, &qB1);
  float lA[4] = {0.f, 0.f, 0.f, 0.f}, lB[4] = {0.f, 0.f, 0.f, 0.f};
  f32x4 oA[4] = {}, oB[4] = {};
  constexpr int NC = (NT + 1) / 2;
  #pragma unroll
  for (int c = 0; c < NC; c++) {
    // --- two score tiles -> exp -> P staged in LDS (both q-tiles) ---
    #pragma unroll
    for (int half = 0; half < 2; half++) {
      constexpr int dummy = 0; (void)dummy;
      int tl = 2 * c + half;
      if (tl < NT) {                         // compile-time per unrolled iter
        bf16x8 b0, b1;
        if (tl == 0) {                       // persistent-mem K from global (L2-hot)
          b0 = *(const bf16x8*)(pmk_h + (size_t)m16 * 64 + quad * 8);
          b1 = *(const bf16x8*)(pmk_h + (size_t)m16 * 64 + 32 + quad * 8);
        } else {
          int row = (tl - 1) * 16 + m16;
          b0 = *(const bf16x8*)(&Ks[row * 72 + quad * 8]);
          b1 = *(const bf16x8*)(&Ks[row * 72 + 32 + quad * 8]);
        }
        f32x4 sA = {0.f, 0.f, 0.f, 0.f}, sB = {0.f, 0.f, 0.f, 0.f};
        sA = __builtin_amdgcn_mfma_f32_16x16x32_bf16(qA0, b0, sA, 0, 0, 0);
        sA = __builtin_amdgcn_mfma_f32_16x16x32_bf16(qA1, b1, sA, 0, 0, 0);
        sB = __builtin_amdgcn_mfma_f32_16x16x32_bf16(qB0, b0, sB, 0, 0, 0);
        sB = __builtin_amdgcn_mfma_f32_16x16x32_bf16(qB1, b1, sB, 0, 0, 0);
        int j = tl * 16 + m16 - 16;          // seq kv index (tile 0 = pm, j<0)
        #pragma unroll
        for (int r = 0; r < 4; r++) {
          float pA = ((tl > 0) && (j > qiA * 16 + quad * 4 + r)) ? 0.f : exp2f(sA[r] * LOG2E);
          float pB = ((tl > 0) && (j > qiB * 16 + quad * 4 + r)) ? 0.f : exp2f(sB[r] * LOG2E);
          lA[r] += pA; lB[r] += pB;
          myP[(quad * 4 + r) * 40 + half * 16 + m16]       = (bf16)pA;
          myP[640 + (quad * 4 + r) * 40 + half * 16 + m16] = (bf16)pB;
        }
      } else {                               // ragged tail half: zero P
        #pragma unroll
        for (int r = 0; r < 4; r++) {
          myP[(quad * 4 + r) * 40 + half * 16 + m16]       = (bf16)0.f;
          myP[640 + (quad * 4 + r) * 40 + half * 16 + m16] = (bf16)0.f;
        }
      }
    }
    // --- PV for this 32-kv chunk; V frags shared by both q-tiles ---
    bf16x8 pfA = *(const bf16x8*)(&myP[m16 * 40 + quad * 8]);
    bf16x8 pfB = *(const bf16x8*)(&myP[640 + m16 * 40 + quad * 8]);
    #pragma unroll
    for (int dt = 0; dt < 4; dt++) {
      bf16x8 vf = *(const bf16x8*)(&Vt[(dt * 16 + m16) * 544 + c * 32 + quad * 8]);
      oA[dt] = __builtin_amdgcn_mfma_f32_16x16x32_bf16(pfA, vf, oA[dt], 0, 0, 0);
      oB[dt] = __builtin_amdgcn_mfma_f32_16x16x32_bf16(pfB, vf, oB[dt], 0, 0, 0);
    }
  }
  // --- reduce l across the 16 j-lanes, normalize, write ---
  #pragma unroll
  for (int r = 0; r < 4; r++) {
    #pragma unroll
    for (int m = 1; m <= 8; m <<= 1) {
      lA[r] += __shfl_xor(lA[r], m, 64);
      lB[r] += __shfl_xor(lB[r], m, 64);
    }
    lA[r] = 1.0f / lA[r];
    lB[r] = 1.0f / lB[r];
  }
  #pragma unroll
  for (int dt = 0; dt < 4; dt++)
    #pragma unroll
    for (int r = 0; r < 4; r++) {
      size_t rowA = (size_t)bw * 512 + qiA * 16 + quad * 4 + r;
      size_t rowB = (size_t)bw * 512 + qiB * 16 + quad * 4 + r;
      ob[rowA * 1024 + h * 64 + dt * 16 + m16] = (bf16)(oA[dt][r] * lA[r]);
      ob[rowB * 1024 + h * 64 + dt * 16 + m16] = (bf16)(oB[dt][r] * lB[r]);
    }
}

// ---------------- attention: one block per (bw,h), 8 waves (512 thr) ----------------
__global__ __launch_bounds__(512) void attn_kernel(const bf16* __restrict__ qkv,
                                                   const bf16* __restrict__ pmbf,
                                                   const float2* __restrict__ tab,
                                                   bf16* __restrict__ ob) {
  __shared__ bf16 Ks[512 * 72];          // seq K rows (rope'd), stride 72 (2-way banks)
  __shared__ bf16 Vt[64 * 544];          // V^T [d][j] incl pm, stride 544, cols 528..543 zero
  __shared__ bf16 Pb[8 * 2 * 16 * 40];   // per-wave 2 P buffers (q-tile A/B), stride 40
  int bh = blockIdx.x;
  int bw = bh >> 4, h = bh & 15;
  int seg = bw & 7;
  int t = threadIdx.x;
  int wv = t >> 6, lane = t & 63;
  int m16 = lane & 15, quad = lane >> 4;
  const bf16* qk_base = qkv + (size_t)bw * 512 * 3072 + h * 64;  // +1024 K, +2048 V
  const bf16* pmk_h = pmbf + (size_t)h * 1024;                    // pm K head h [16][64]
  // stage seq K rows with rope: 512 rows x 8 chunks of 16B
  #pragma unroll
  for (int it = 0; it < 8; it++) {
    int ch = t + it * 512;
    int row = ch >> 3, c8 = (ch & 7) * 8;
    bf16 tmp[8];
    *(uint4*)tmp = *(const uint4*)(qk_base + (size_t)row * 3072 + 1024 + c8);
    const float2* tb = tab + (seg * 512 + row) * 32 + (c8 >> 1);
    #pragma unroll
    for (int p = 0; p < 4; p++) {
      float2 cs = tb[p];
      float x0 = (float)tmp[2 * p], x1 = (float)tmp[2 * p + 1];
      tmp[2 * p]     = (bf16)(x0 * cs.x - x1 * cs.y);
      tmp[2 * p + 1] = (bf16)(x1 * cs.x + x0 * cs.y);
    }
    *(uint4*)(&Ks[row * 72 + c8]) = *(uint4*)tmp;
  }
  // stage V transposed, d0-major per wave (lanes span rows -> ~2-way store banks)
  {
    int d0 = wv * 8;
    #pragma unroll
    for (int it = 0; it < 9; it++) {
      int row = it * 64 + lane;
      if (it < 8 || lane < 16) {           // rows 0..527
        bf16 tmp[8];
        if (row < 16) *(uint4*)tmp = *(const uint4*)(pmbf + ((size_t)(16 + h) * 16 + row) * 64 + d0);
        else          *(uint4*)tmp = *(const uint4*)(qk_base + (size_t)(row - 16) * 3072 + 2048 + d0);
        #pragma unroll
        for (int i = 0; i < 8; i++) Vt[(d0 + i) * 544 + row] = tmp[i];
      }
    }
  }
  // zero-pad Vt cols 528..543 (read by ragged last chunk with P=0)
  { int r = t >> 3, cc = 528 + (t & 7) * 2; *(unsigned int*)(&Vt[r * 544 + cc]) = 0u; }
  __syncthreads();

  bf16* myP = &Pb[wv * 2 * 16 * 40];
  attn_pass2<17>(wv,      15 - wv, qk_base, pmk_h, Ks, Vt, myP, tab, ob, bw, h, seg, m16, quad);
  attn_pass2<33>(16 + wv, 31 - wv, qk_base, pmk_h, Ks, Vt, myP, tab, ob, bw, h, seg, m16, quad);
}

// ---------------- launch ----------------
extern "C" void kernel_launch(void* const* d_in, const int* in_sizes, int n_in,
                              void* d_out, int out_size, void* d_ws, size_t ws_size,
                              hipStream_t stream) {
  const float* seq  = (const float*)d_in[0];
  const float* g    = (const float*)d_in[1];
  const float* wqkv = (const float*)d_in[2];
  const float* wout = (const float*)d_in[3];
  const float* pm   = (const float*)d_in[4];
  float* out = (float*)d_out;
  char* ws = (char*)d_ws;
  bf16*   wqkv_bf = (bf16*)(ws);                  //  6,291,456
  bf16*   wout_bf = (bf16*)(ws + 6291456);        //  2,097,152
  bf16*   pm_bf   = (bf16*)(ws + 8388608);        //     65,536
  float2* tab     = (float2*)(ws + 8454144);      //  1,048,576 (4096 x 32 cos/sin)
  bf16*   x_bf    = (bf16*)(ws + 9502720);        // 16,777,216 (RMSNorm out, reused as attn out)
  bf16*   qkv_bf  = (bf16*)(ws + 26279936);       // 50,331,648 -> 76,611,584 total

  cast3_kernel<<<4640, 256, 0, stream>>>(wqkv, 786432, wqkv_bf,
                                         wout, 262144, wout_bf,
                                         pm, 8192, pm_bf,
                                         tab, 131072);
  rmsnorm_kernel<<<8192, 256, 0, stream>>>(seq, g, x_bf);
  gemm_bt_kernel<0><<<dim3(24, 64), 256, 0, stream>>>(x_bf, wqkv_bf, qkv_bf, 8192, 3072, 1024);
  attn_kernel<<<256, 512, 0, stream>>>(qkv_bf, pm_bf, tab, x_bf);
  gemm_bt_kernel<1><<<dim3(8, 64), 256, 0, stream>>>(x_bf, wout_bf, out, 8192, 1024, 1024);
}

// Round 7
// 258.594 us; speedup vs baseline: 1.7072x; 1.0036x over previous
//
#include <hip/hip_runtime.h>

typedef __bf16 bf16;
typedef __bf16 bf16x4 __attribute__((ext_vector_type(4)));
typedef __bf16 bf16x8 __attribute__((ext_vector_type(8)));
typedef float f32x4 __attribute__((ext_vector_type(4)));

#define LOG2E 1.44269504088896f

// async global->LDS, 16B per lane. LDS dest is wave-uniform base + lane*16
// (m104/m108): pass the lane-0 pointer; generic->AS(3) = low-32-bit truncation.
__device__ __forceinline__ void gl_lds16(const bf16* g, bf16* l) {
  __builtin_amdgcn_global_load_lds(
      reinterpret_cast<const __attribute__((address_space(1))) void*>((uintptr_t)g),
      reinterpret_cast<__attribute__((address_space(3))) void*>((uint32_t)(uintptr_t)l),
      16, 0, 0);
}

// ---------------- cast fp32 -> bf16 for weights + pm, and build RoPE cos/sin table ----------------
__global__ void cast3_kernel(const float* __restrict__ a, int na4, bf16* __restrict__ oa,
                             const float* __restrict__ b, int nb4, bf16* __restrict__ ob,
                             const float* __restrict__ c, int nc4, bf16* __restrict__ oc,
                             float2* __restrict__ tab, int nt) {
  int i = blockIdx.x * blockDim.x + threadIdx.x;
  if (i < na4 + nb4 + nc4) {
    const float* src; bf16* dst; int idx;
    if (i < na4)            { src = a; dst = oa; idx = i; }
    else if (i < na4 + nb4) { src = b; dst = ob; idx = i - na4; }
    else                    { src = c; dst = oc; idx = i - na4 - nb4; }
    float4 v = ((const float4*)src)[idx];
    bf16x4 o = { (bf16)v.x, (bf16)v.y, (bf16)v.z, (bf16)v.w };
    ((bf16x4*)dst)[idx] = o;
  } else {
    int idx = i - (na4 + nb4 + nc4);
    if (idx >= nt) return;
    int pos = idx >> 5, fi = idx & 31;
    float inv = exp2f((float)fi * -0.41524101186f);   // 10000^(-fi/32)
    float th = (float)pos * inv;
    float sn, cs;
    sincosf(th, &sn, &cs);
    tab[idx] = make_float2(cs, sn);
  }
}

// ---------------- RMSNorm: seq fp32 [8192][1024] -> x bf16 ----------------
__global__ __launch_bounds__(256) void rmsnorm_kernel(const float* __restrict__ seq,
                                                      const float* __restrict__ g,
                                                      bf16* __restrict__ xbf) {
  int row = blockIdx.x;
  int t = threadIdx.x;
  float4 x = ((const float4*)(seq + (size_t)row * 1024))[t];
  float ss = x.x*x.x + x.y*x.y + x.z*x.z + x.w*x.w;
  #pragma unroll
  for (int m = 32; m >= 1; m >>= 1) ss += __shfl_xor(ss, m, 64);
  __shared__ float red[4];
  if ((t & 63) == 0) red[t >> 6] = ss;
  __syncthreads();
  float tot = red[0] + red[1] + red[2] + red[3];
  float scale = rsqrtf(tot * (1.0f / 1024.0f) + 1.1920929e-07f);
  float4 gv = ((const float4*)g)[t];
  bf16x4 o = { (bf16)(x.x*scale*gv.x), (bf16)(x.y*scale*gv.y),
               (bf16)(x.z*scale*gv.z), (bf16)(x.w*scale*gv.w) };
  ((bf16x4*)(xbf + (size_t)row * 1024))[t] = o;
}

// ---------------- GEMM C[M,N] = A[M,K] * B[N,K]^T  (bf16 in, bf16/fp32 out) ----------------
// BK=64, XOR-swizzled LDS, global_load_lds width=16 (m97 lineage).
template<int OUTF>
__global__ __launch_bounds__(256) void gemm_bt_kernel(const bf16* __restrict__ A,
                                                      const bf16* __restrict__ B,
                                                      void* __restrict__ C,
                                                      int M, int N, int K) {
  __shared__ bf16 As[128 * 64];
  __shared__ bf16 Bs[128 * 64];
  int t = threadIdx.x;
  int lane = t & 63, wv = t >> 6;
  int m16 = lane & 15, quad = lane >> 4;
  int bn = blockIdx.x, bm = blockIdx.y;
  const bf16* Ab = A + (size_t)bm * 128 * K;
  const bf16* Bb = B + (size_t)bn * 128 * K;
  int wr = (wv >> 1) * 64, wc = (wv & 1) * 64;
  f32x4 acc[4][4] = {};
  for (int k0 = 0; k0 < K; k0 += 64) {
    #pragma unroll
    for (int i = 0; i < 4; i++) {
      int cb = i * 256 + wv * 64;          // wave-uniform chunk base (16B chunks)
      int s = cb + lane;
      int row = s >> 3, p = s & 7, g = p ^ (row & 7);
      gl_lds16(Ab + (size_t)row * K + k0 + g * 8, &As[cb * 8]);
      gl_lds16(Bb + (size_t)row * K + k0 + g * 8, &Bs[cb * 8]);
    }
    __syncthreads();   // implicit s_waitcnt vmcnt(0) drains the LDS-DMA
    #pragma unroll
    for (int kk = 0; kk < 2; kk++) {
      bf16x8 af[4], bfr[4];
      #pragma unroll
      for (int i = 0; i < 4; i++) {
        int row = wr + i * 16 + m16;
        int p = (kk * 4 + quad) ^ (row & 7);
        af[i] = *(const bf16x8*)(&As[row * 64 + p * 8]);
      }
      #pragma unroll
      for (int j = 0; j < 4; j++) {
        int row = wc + j * 16 + m16;
        int p = (kk * 4 + quad) ^ (row & 7);
        bfr[j] = *(const bf16x8*)(&Bs[row * 64 + p * 8]);
      }
      #pragma unroll
      for (int i = 0; i < 4; i++)
        #pragma unroll
        for (int j = 0; j < 4; j++)
          acc[i][j] = __builtin_amdgcn_mfma_f32_16x16x32_bf16(af[i], bfr[j], acc[i][j], 0, 0, 0);
    }
    __syncthreads();
  }
  #pragma unroll
  for (int i = 0; i < 4; i++)
    #pragma unroll
    for (int j = 0; j < 4; j++)
      #pragma unroll
      for (int r = 0; r < 4; r++) {
        size_t row = (size_t)bm * 128 + wr + i * 16 + quad * 4 + r;
        size_t col = (size_t)bn * 128 + wc + j * 16 + m16;
        float v = acc[i][j][r];
        if (OUTF) ((float*)C)[row * N + col] = v;
        else      ((bf16*)C)[row * N + col] = (bf16)v;
      }
}

// ---------------- attention helpers ----------------
__device__ __forceinline__ void load_q_frag(const bf16* qk_base, const float2* tab,
                                            int seg, int qi, int m16, int quad,
                                            bf16x8* f0, bf16x8* f1) {
  int qrow = qi * 16 + m16;
  const bf16* qp = qk_base + (size_t)qrow * 3072;
  bf16 qr0[8], qr1[8];
  *(uint4*)qr0 = *(const uint4*)(qp + quad * 8);
  *(uint4*)qr1 = *(const uint4*)(qp + 32 + quad * 8);
  const float2* tb0 = tab + (seg * 512 + qrow) * 32 + quad * 4;
  const float2* tb1 = tb0 + 16;
  #pragma unroll
  for (int p = 0; p < 4; p++) {
    float2 c0 = tb0[p], c1 = tb1[p];
    float a0 = (float)qr0[2 * p], a1 = (float)qr0[2 * p + 1];
    qr0[2 * p]     = (bf16)((a0 * c0.x - a1 * c0.y) * 0.125f);
    qr0[2 * p + 1] = (bf16)((a1 * c0.x + a0 * c0.y) * 0.125f);
    float b0 = (float)qr1[2 * p], b1 = (float)qr1[2 * p + 1];
    qr1[2 * p]     = (bf16)((b0 * c1.x - b1 * c1.y) * 0.125f);
    qr1[2 * p + 1] = (bf16)((b1 * c1.x + b0 * c1.y) * 0.125f);
  }
  *f0 = *(bf16x8*)qr0;
  *f1 = *(bf16x8*)qr1;
}

// Pass over NT score tiles for TWO q-tiles sharing every K/V fragment read.
// m=0 softmax: scores bounded (|s|<~30 << f32 overflow at 88) -> skip max pass,
// exp immediately, accumulate l, one cross-lane reduction at the end.
template<int NT>
__device__ __forceinline__ void attn_pass2(int qiA, int qiB, const bf16* qk_base,
                                           const bf16* pmk_h, const bf16* Ks,
                                           const bf16* Vt, bf16* myP,
                                           const float2* tab, bf16* ob,
                                           int bw, int h, int seg, int m16, int quad) {
  bf16x8 qA0, qA1, qB0, qB1;
  load_q_frag(qk_base, tab, seg, qiA, m16, quad, &qA0, &qA1);
  load_q_frag(qk_base, tab, seg, qiB, m16, quad, &qB0, &qB1);
  float lA[4] = {0.f, 0.f, 0.f, 0.f}, lB[4] = {0.f, 0.f, 0.f, 0.f};
  f32x4 oA[4] = {}, oB[4] = {};
  constexpr int NC = (NT + 1) / 2;
  #pragma unroll
  for (int c = 0; c < NC; c++) {
    // --- two score tiles -> exp -> P staged in LDS (both q-tiles) ---
    #pragma unroll
    for (int half = 0; half < 2; half++) {
      int tl = 2 * c + half;
      if (tl < NT) {                         // compile-time per unrolled iter
        bf16x8 b0, b1;
        if (tl == 0) {                       // persistent-mem K from global (L2-hot)
          b0 = *(const bf16x8*)(pmk_h + (size_t)m16 * 64 + quad * 8);
          b1 = *(const bf16x8*)(pmk_h + (size_t)m16 * 64 + 32 + quad * 8);
        } else {
          int row = (tl - 1) * 16 + m16;
          b0 = *(const bf16x8*)(&Ks[row * 72 + quad * 8]);
          b1 = *(const bf16x8*)(&Ks[row * 72 + 32 + quad * 8]);
        }
        f32x4 sA = {0.f, 0.f, 0.f, 0.f}, sB = {0.f, 0.f, 0.f, 0.f};
        sA = __builtin_amdgcn_mfma_f32_16x16x32_bf16(qA0, b0, sA, 0, 0, 0);
        sA = __builtin_amdgcn_mfma_f32_16x16x32_bf16(qA1, b1, sA, 0, 0, 0);
        sB = __builtin_amdgcn_mfma_f32_16x16x32_bf16(qB0, b0, sB, 0, 0, 0);
        sB = __builtin_amdgcn_mfma_f32_16x16x32_bf16(qB1, b1, sB, 0, 0, 0);
        int j = tl * 16 + m16 - 16;          // seq kv index (tile 0 = pm, j<0)
        #pragma unroll
        for (int r = 0; r < 4; r++) {
          float pA = ((tl > 0) && (j > qiA * 16 + quad * 4 + r)) ? 0.f : exp2f(sA[r] * LOG2E);
          float pB = ((tl > 0) && (j > qiB * 16 + quad * 4 + r)) ? 0.f : exp2f(sB[r] * LOG2E);
          lA[r] += pA; lB[r] += pB;
          myP[(quad * 4 + r) * 40 + half * 16 + m16]       = (bf16)pA;
          myP[640 + (quad * 4 + r) * 40 + half * 16 + m16] = (bf16)pB;
        }
      } else {                               // ragged tail half: zero P
        #pragma unroll
        for (int r = 0; r < 4; r++) {
          myP[(quad * 4 + r) * 40 + half * 16 + m16]       = (bf16)0.f;
          myP[640 + (quad * 4 + r) * 40 + half * 16 + m16] = (bf16)0.f;
        }
      }
    }
    // --- PV for this 32-kv chunk; V frags shared by both q-tiles ---
    bf16x8 pfA = *(const bf16x8*)(&myP[m16 * 40 + quad * 8]);
    bf16x8 pfB = *(const bf16x8*)(&myP[640 + m16 * 40 + quad * 8]);
    #pragma unroll
    for (int dt = 0; dt < 4; dt++) {
      bf16x8 vf = *(const bf16x8*)(&Vt[(dt * 16 + m16) * 544 + c * 32 + quad * 8]);
      oA[dt] = __builtin_amdgcn_mfma_f32_16x16x32_bf16(pfA, vf, oA[dt], 0, 0, 0);
      oB[dt] = __builtin_amdgcn_mfma_f32_16x16x32_bf16(pfB, vf, oB[dt], 0, 0, 0);
    }
  }
  // --- reduce l across the 16 j-lanes, normalize, write ---
  #pragma unroll
  for (int r = 0; r < 4; r++) {
    #pragma unroll
    for (int m = 1; m <= 8; m <<= 1) {
      lA[r] += __shfl_xor(lA[r], m, 64);
      lB[r] += __shfl_xor(lB[r], m, 64);
    }
    lA[r] = 1.0f / lA[r];
    lB[r] = 1.0f / lB[r];
  }
  #pragma unroll
  for (int dt = 0; dt < 4; dt++)
    #pragma unroll
    for (int r = 0; r < 4; r++) {
      size_t rowA = (size_t)bw * 512 + qiA * 16 + quad * 4 + r;
      size_t rowB = (size_t)bw * 512 + qiB * 16 + quad * 4 + r;
      ob[rowA * 1024 + h * 64 + dt * 16 + m16] = (bf16)(oA[dt][r] * lA[r]);
      ob[rowB * 1024 + h * 64 + dt * 16 + m16] = (bf16)(oB[dt][r] * lB[r]);
    }
}

// ---------------- attention: one block per (bw,h), 8 waves (512 thr) ----------------
// __launch_bounds__(512, 2): LDS (160 KB) caps the CU at 1 block = 2 waves/SIMD
// anyway, so declare it -> 256-VGPR budget -> no scratch spill (R5 post-mortem:
// bare (512) budgeted 128 VGPR for an occupancy LDS can never deliver, spilling
// ~53 MB/dispatch to scratch).
__global__ __launch_bounds__(512, 2) void attn_kernel(const bf16* __restrict__ qkv,
                                                      const bf16* __restrict__ pmbf,
                                                      const float2* __restrict__ tab,
                                                      bf16* __restrict__ ob) {
  __shared__ bf16 Ks[512 * 72];          // seq K rows (rope'd), stride 72 (2-way banks)
  __shared__ bf16 Vt[64 * 544];          // V^T [d][j] incl pm, stride 544, cols 528..543 zero
  __shared__ bf16 Pb[8 * 2 * 16 * 40];   // per-wave 2 P buffers (q-tile A/B), stride 40
  int bh = blockIdx.x;
  int bw = bh >> 4, h = bh & 15;
  int seg = bw & 7;
  int t = threadIdx.x;
  int wv = t >> 6, lane = t & 63;
  int m16 = lane & 15, quad = lane >> 4;
  const bf16* qk_base = qkv + (size_t)bw * 512 * 3072 + h * 64;  // +1024 K, +2048 V
  const bf16* pmk_h = pmbf + (size_t)h * 1024;                    // pm K head h [16][64]
  // stage seq K rows with rope: 512 rows x 8 chunks of 16B
  #pragma unroll
  for (int it = 0; it < 8; it++) {
    int ch = t + it * 512;
    int row = ch >> 3, c8 = (ch & 7) * 8;
    bf16 tmp[8];
    *(uint4*)tmp = *(const uint4*)(qk_base + (size_t)row * 3072 + 1024 + c8);
    const float2* tb = tab + (seg * 512 + row) * 32 + (c8 >> 1);
    #pragma unroll
    for (int p = 0; p < 4; p++) {
      float2 cs = tb[p];
      float x0 = (float)tmp[2 * p], x1 = (float)tmp[2 * p + 1];
      tmp[2 * p]     = (bf16)(x0 * cs.x - x1 * cs.y);
      tmp[2 * p + 1] = (bf16)(x1 * cs.x + x0 * cs.y);
    }
    *(uint4*)(&Ks[row * 72 + c8]) = *(uint4*)tmp;
  }
  // stage V transposed, d0-major per wave (lanes span rows -> ~2-way store banks)
  {
    int d0 = wv * 8;
    #pragma unroll
    for (int it = 0; it < 9; it++) {
      int row = it * 64 + lane;
      if (it < 8 || lane < 16) {           // rows 0..527
        bf16 tmp[8];
        if (row < 16) *(uint4*)tmp = *(const uint4*)(pmbf + ((size_t)(16 + h) * 16 + row) * 64 + d0);
        else          *(uint4*)tmp = *(const uint4*)(qk_base + (size_t)(row - 16) * 3072 + 2048 + d0);
        #pragma unroll
        for (int i = 0; i < 8; i++) Vt[(d0 + i) * 544 + row] = tmp[i];
      }
    }
  }
  // zero-pad Vt cols 528..543 (read by ragged last chunk with P=0)
  { int r = t >> 3, cc = 528 + (t & 7) * 2; *(unsigned int*)(&Vt[r * 544 + cc]) = 0u; }
  __syncthreads();

  bf16* myP = &Pb[wv * 2 * 16 * 40];
  attn_pass2<17>(wv,      15 - wv, qk_base, pmk_h, Ks, Vt, myP, tab, ob, bw, h, seg, m16, quad);
  attn_pass2<33>(16 + wv, 31 - wv, qk_base, pmk_h, Ks, Vt, myP, tab, ob, bw, h, seg, m16, quad);
}

// ---------------- launch ----------------
extern "C" void kernel_launch(void* const* d_in, const int* in_sizes, int n_in,
                              void* d_out, int out_size, void* d_ws, size_t ws_size,
                              hipStream_t stream) {
  const float* seq  = (const float*)d_in[0];
  const float* g    = (const float*)d_in[1];
  const float* wqkv = (const float*)d_in[2];
  const float* wout = (const float*)d_in[3];
  const float* pm   = (const float*)d_in[4];
  float* out = (float*)d_out;
  char* ws = (char*)d_ws;
  bf16*   wqkv_bf = (bf16*)(ws);                  //  6,291,456
  bf16*   wout_bf = (bf16*)(ws + 6291456);        //  2,097,152
  bf16*   pm_bf   = (bf16*)(ws + 8388608);        //     65,536
  float2* tab     = (float2*)(ws + 8454144);      //  1,048,576 (4096 x 32 cos/sin)
  bf16*   x_bf    = (bf16*)(ws + 9502720);        // 16,777,216 (RMSNorm out, reused as attn out)
  bf16*   qkv_bf  = (bf16*)(ws + 26279936);       // 50,331,648 -> 76,611,584 total

  cast3_kernel<<<4640, 256, 0, stream>>>(wqkv, 786432, wqkv_bf,
                                         wout, 262144, wout_bf,
                                         pm, 8192, pm_bf,
                                         tab, 131072);
  rmsnorm_kernel<<<8192, 256, 0, stream>>>(seq, g, x_bf);
  gemm_bt_kernel<0><<<dim3(24, 64), 256, 0, stream>>>(x_bf, wqkv_bf, qkv_bf, 8192, 3072, 1024);
  attn_kernel<<<256, 512, 0, stream>>>(qkv_bf, pm_bf, tab, x_bf);
  gemm_bt_kernel<1><<<dim3(8, 64), 256, 0, stream>>>(x_bf, wout_bf, out, 8192, 1024, 1024);
}